// Round 2
// baseline (641.426 us; speedup 1.0000x reference)
//
#include <hip/hip_runtime.h>
#include <hip/hip_bf16.h>
#include <stdint.h>

// B=16, S=2048, D=64. All fp32 I/O; mask int32 (nonzero == masked -> -1e30).
// d_in: q[B,S,D] f32, k[B,S,D] f32, v[B,S,D] f32, mask[B,S,S] i32
// d_out: output[B,S,D] f32 (2097152 floats) then attn[B,S,S] f32.
//
// v2b path (needs 12 MB workspace):
//   prep_k: K f32 -> k_hi,k_lo bf16 [B,S,D]   (hi/lo split for 3-term MFMA)
//   prep_v: V f32 -> vt bf16 [B,D,S]          (transpose -> vector B-frag loads)
//   attn_fused_v2b: exact v1 control flow (ALL barriers kept, plain loads/
//   stores) but K/V fragments come pre-converted -> no per-block f32->bf16
//   VALU work, and V B-frags are single 16B vector loads instead of 8 scalar
//   dword gathers.
// Fallback: original proven v1 kernel if ws too small.

#define S_DIM 2048
#define D_DIM 64

typedef short short8 __attribute__((ext_vector_type(8)));
typedef float floatx4 __attribute__((ext_vector_type(4)));
typedef unsigned short ushort4v __attribute__((ext_vector_type(4)));
typedef unsigned short ushort8v __attribute__((ext_vector_type(8)));

__device__ __forceinline__ unsigned short f2bf(float x) {
    uint32_t u = __float_as_uint(x);
    u += 0x7fffu + ((u >> 16) & 1u);
    return (unsigned short)(u >> 16);
}
__device__ __forceinline__ float bf2f(unsigned short h) {
    return __uint_as_float((uint32_t)h << 16);
}

// ---------------------------------------------------------------------------
// Pre-pass: K -> hi/lo bf16 (elementwise). grid 2048 x 256, 4 floats/thread.
__global__ __launch_bounds__(256) void prep_k(
    const float* __restrict__ k,
    unsigned short* __restrict__ khi, unsigned short* __restrict__ klo)
{
    size_t i = ((size_t)blockIdx.x * 256 + threadIdx.x) * 4;
    float4 x = *(const float4*)(k + i);
    float xs[4] = {x.x, x.y, x.z, x.w};
    ushort4v h, l;
    #pragma unroll
    for (int p = 0; p < 4; ++p) {
        unsigned short hp = f2bf(xs[p]);
        h[p] = hp;
        l[p] = f2bf(xs[p] - bf2f(hp));
    }
    *(ushort4v*)(khi + i) = h;
    *(ushort4v*)(klo + i) = l;
}

// Pre-pass: V [B,S,D] f32 -> vt [B,D,S] bf16 (tiled transpose via LDS).
// grid 16*32 blocks (64-key tile per block), 256 threads.
__global__ __launch_bounds__(256) void prep_v(
    const float* __restrict__ v, unsigned short* __restrict__ vt)
{
    __shared__ unsigned short tile[64][66];
    const int b  = blockIdx.x >> 5;
    const int s0 = (blockIdx.x & 31) * 64;
    #pragma unroll
    for (int i = 0; i < 4; ++i) {
        int e = threadIdx.x + i * 256;        // float4 slot in 64x64 tile
        int key = e >> 4, d4 = (e & 15) * 4;
        float4 x = *(const float4*)(v + ((size_t)(b * S_DIM + s0 + key)) * D_DIM + d4);
        tile[key][d4 + 0] = f2bf(x.x);
        tile[key][d4 + 1] = f2bf(x.y);
        tile[key][d4 + 2] = f2bf(x.z);
        tile[key][d4 + 3] = f2bf(x.w);
    }
    __syncthreads();
    const int d  = threadIdx.x >> 2;
    const int k0 = (threadIdx.x & 3) * 16;
    union { unsigned short u[16]; ushort8v v8[2]; } T;
    #pragma unroll
    for (int j = 0; j < 16; ++j) T.u[j] = tile[k0 + j][d];
    unsigned short* dst = vt + ((size_t)(b * D_DIM + d)) * S_DIM + s0 + k0;
    *(ushort8v*)dst       = T.v8[0];
    *(ushort8v*)(dst + 8) = T.v8[1];
}

// ---------------------------------------------------------------------------
// Main kernel v2b: v1 control flow (all barriers), prep-converted K/V.
__global__ __launch_bounds__(512) void attn_fused_v2b(
    const float* __restrict__ q,
    const unsigned short* __restrict__ khi, const unsigned short* __restrict__ klo,
    const unsigned short* __restrict__ vt,
    const int* __restrict__ mask,
    float* __restrict__ out, float* __restrict__ attn)
{
    __shared__ __align__(16) float qlds[16 * 68];              // 4.4 KB
    __shared__ __align__(16) unsigned short pbuf[8 * 16 * 36]; // 9.2 KB
    __shared__ __align__(16) float obuf[8 * 16 * 68];          // 34.8 KB
    __shared__ float mxtab[8 * 16];
    __shared__ float ltab[8 * 16];

    const int tid  = threadIdx.x;
    const int w    = tid >> 6;
    const int lane = tid & 63;
    const int quad = lane >> 4;
    const int n16  = lane & 15;
    const int b    = blockIdx.x >> 7;     // 128 q-tiles per batch
    const int q0   = (blockIdx.x & 127) * 16;
    const int key0 = w * 256;

    // ---------------- Phase A: Q tile -> LDS, build A-frags (hi/lo) -------
    {
        int m = tid >> 5, d = (tid & 31) * 2;
        float2 qv = *(const float2*)(q + ((size_t)(b * S_DIM + q0 + m)) * D_DIM + d);
        qlds[m * 68 + d]     = qv.x;
        qlds[m * 68 + d + 1] = qv.y;
    }
    __syncthreads();

    short8 ahi[2], alo[2];
    #pragma unroll
    for (int s = 0; s < 2; ++s) {
        const float* qp = &qlds[n16 * 68 + s * 32 + quad * 8];
        union { unsigned short u[8]; short8 v; } H, L;
        #pragma unroll
        for (int p = 0; p < 8; ++p) {
            float x = qp[p];
            unsigned short hp = f2bf(x);
            H.u[p] = hp;
            L.u[p] = f2bf(x - bf2f(hp));
        }
        ahi[s] = H.v; alo[s] = L.v;
    }

    // ---------------- Phase B: scores = QK^T/8, masked --------------------
    floatx4 sc[16];
    const unsigned short* khb = khi + (size_t)(b * S_DIM) * D_DIM;
    const unsigned short* klb = klo + (size_t)(b * S_DIM) * D_DIM;
    #pragma unroll
    for (int c = 0; c < 16; ++c) {
        const int key = key0 + c * 16 + n16;
        const int* mp = mask + (size_t)(b * S_DIM + q0 + quad * 4) * S_DIM + key;
        int mk0 = mp[0], mk1 = mp[S_DIM], mk2 = mp[2 * S_DIM], mk3 = mp[3 * S_DIM];
        floatx4 acc = {0.f, 0.f, 0.f, 0.f};
        #pragma unroll
        for (int s = 0; s < 2; ++s) {
            const size_t off = (size_t)key * D_DIM + s * 32 + quad * 8;
            short8 BH = *(const short8*)(khb + off);
            short8 BL = *(const short8*)(klb + off);
            acc = __builtin_amdgcn_mfma_f32_16x16x32_bf16(ahi[s], BH, acc, 0, 0, 0);
            acc = __builtin_amdgcn_mfma_f32_16x16x32_bf16(ahi[s], BL, acc, 0, 0, 0);
            acc = __builtin_amdgcn_mfma_f32_16x16x32_bf16(alo[s], BH, acc, 0, 0, 0);
        }
        sc[c][0] = mk0 ? -1e30f : acc[0] * 0.125f;
        sc[c][1] = mk1 ? -1e30f : acc[1] * 0.125f;
        sc[c][2] = mk2 ? -1e30f : acc[2] * 0.125f;
        sc[c][3] = mk3 ? -1e30f : acc[3] * 0.125f;
    }

    // ---------------- Phase C: exact softmax over 2048 keys ---------------
    #pragma unroll
    for (int r = 0; r < 4; ++r) {
        float mx = sc[0][r];
        #pragma unroll
        for (int c = 1; c < 16; ++c) mx = fmaxf(mx, sc[c][r]);
        #pragma unroll
        for (int o = 1; o < 16; o <<= 1) mx = fmaxf(mx, __shfl_xor(mx, o, 64));
        if (n16 == 0) mxtab[w * 16 + quad * 4 + r] = mx;
    }
    __syncthreads();
    #pragma unroll
    for (int r = 0; r < 4; ++r) {
        float mf = -3e38f;
        #pragma unroll
        for (int w2 = 0; w2 < 8; ++w2) mf = fmaxf(mf, mxtab[w2 * 16 + quad * 4 + r]);
        float l = 0.f;
        #pragma unroll
        for (int c = 0; c < 16; ++c) {
            float e = __expf(sc[c][r] - mf);
            sc[c][r] = e;
            l += e;
        }
        #pragma unroll
        for (int o = 1; o < 16; o <<= 1) l += __shfl_xor(l, o, 64);
        if (n16 == 0) ltab[w * 16 + quad * 4 + r] = l;
    }
    __syncthreads();
    #pragma unroll
    for (int r = 0; r < 4; ++r) {
        float l = 0.f;
        #pragma unroll
        for (int w2 = 0; w2 < 8; ++w2) l += ltab[w2 * 16 + quad * 4 + r];
        float inv = 1.0f / l;
        #pragma unroll
        for (int c = 0; c < 16; ++c) sc[c][r] *= inv;
    }

    // ---------------- Phase D: write attn (fp32, 64B-coalesced/quad) ------
    {
        float* arow = attn + (size_t)(b * S_DIM + q0 + quad * 4) * S_DIM + key0 + n16;
        #pragma unroll
        for (int c = 0; c < 16; ++c) {
            #pragma unroll
            for (int r = 0; r < 4; ++r) arow[(size_t)r * S_DIM + c * 16] = sc[c][r];
        }
    }

    // ---------------- Phase E: O += P*V (bf16 MFMA), P via LDS transpose --
    // Barriers kept exactly as v1 (proven correct).
    floatx4 o0 = {0,0,0,0}, o1 = {0,0,0,0}, o2 = {0,0,0,0}, o3 = {0,0,0,0};
    unsigned short* pw = pbuf + w * 576;   // 16 rows x 36 (32 keys + pad)
    const unsigned short* vtb = vt + (size_t)b * D_DIM * S_DIM;
    #pragma unroll
    for (int s2 = 0; s2 < 8; ++s2) {
        #pragma unroll
        for (int h = 0; h < 2; ++h) {
            const int c = s2 * 2 + h;
            #pragma unroll
            for (int r = 0; r < 4; ++r)
                pw[(quad * 4 + r) * 36 + h * 16 + n16] = f2bf(sc[c][r]);
        }
        __syncthreads();
        short8 pa;
        {
            const uint32_t* pr = (const uint32_t*)((const char*)pbuf +
                                   (size_t)w * 1152 + n16 * 72 + quad * 16);
            union { uint32_t u[4]; short8 v; } P;
            P.u[0] = pr[0]; P.u[1] = pr[1]; P.u[2] = pr[2]; P.u[3] = pr[3];
            pa = P.v;
        }
        const int keyb = key0 + s2 * 32 + quad * 8;
        #pragma unroll
        for (int nc = 0; nc < 4; ++nc) {
            short8 bv = *(const short8*)(vtb + (size_t)(nc * 16 + n16) * S_DIM + keyb);
            floatx4& oo = (nc == 0 ? o0 : nc == 1 ? o1 : nc == 2 ? o2 : o3);
            oo = __builtin_amdgcn_mfma_f32_16x16x32_bf16(pa, bv, oo, 0, 0, 0);
        }
        __syncthreads();
    }

    // ---------------- Phase F: reduce per-wave partial O, store -----------
    #pragma unroll
    for (int nc = 0; nc < 4; ++nc) {
        floatx4 oo = (nc == 0 ? o0 : nc == 1 ? o1 : nc == 2 ? o2 : o3);
        #pragma unroll
        for (int i = 0; i < 4; ++i)
            obuf[(w * 16 + quad * 4 + i) * 68 + nc * 16 + n16] = oo[i];
    }
    __syncthreads();
    #pragma unroll
    for (int t2 = 0; t2 < 2; ++t2) {
        int idx = tid + t2 * 512;
        int m = idx >> 6, d = idx & 63;
        float a = 0.f;
        #pragma unroll
        for (int w2 = 0; w2 < 8; ++w2) a += obuf[(w2 * 16 + m) * 68 + d];
        out[(size_t)(b * S_DIM + q0 + m) * D_DIM + d] = a;
    }
}

// ---------------------------------------------------------------------------
// Fallback v1 (proven at 648.5 us) — used only if workspace is too small.
__global__ __launch_bounds__(512) void attn_fused_v1(
    const float* __restrict__ q, const float* __restrict__ k,
    const float* __restrict__ v, const int* __restrict__ mask,
    float* __restrict__ out, float* __restrict__ attn)
{
    __shared__ __align__(16) float qlds[16 * 68];
    __shared__ __align__(16) unsigned short pbuf[8 * 16 * 36];
    __shared__ __align__(16) float obuf[8 * 16 * 68];
    __shared__ float mxtab[8 * 16];
    __shared__ float ltab[8 * 16];

    const int tid  = threadIdx.x;
    const int w    = tid >> 6;
    const int lane = tid & 63;
    const int quad = lane >> 4;
    const int n16  = lane & 15;
    const int b    = blockIdx.x >> 7;
    const int q0   = (blockIdx.x & 127) * 16;
    const int key0 = w * 256;

    {
        int m = tid >> 5, d = (tid & 31) * 2;
        float2 qv = *(const float2*)(q + ((size_t)(b * S_DIM + q0 + m)) * D_DIM + d);
        qlds[m * 68 + d]     = qv.x;
        qlds[m * 68 + d + 1] = qv.y;
    }
    __syncthreads();

    short8 ahi[2], alo[2];
    #pragma unroll
    for (int s = 0; s < 2; ++s) {
        const float* qp = &qlds[n16 * 68 + s * 32 + quad * 8];
        union { __hip_bfloat162 h[4]; short8 v; } H, L;
        #pragma unroll
        for (int p = 0; p < 4; ++p) {
            float x0 = qp[2 * p], x1 = qp[2 * p + 1];
            __hip_bfloat162 h2 = __float22bfloat162_rn(float2{x0, x1});
            float l0 = x0 - __bfloat162float(h2.x);
            float l1 = x1 - __bfloat162float(h2.y);
            H.h[p] = h2;
            L.h[p] = __float22bfloat162_rn(float2{l0, l1});
        }
        ahi[s] = H.v; alo[s] = L.v;
    }

    floatx4 sc[16];
    const size_t kvbase = (size_t)(b * S_DIM) * D_DIM;
    #pragma unroll
    for (int c = 0; c < 16; ++c) {
        const int key = key0 + c * 16 + n16;
        const int* mp = mask + (size_t)(b * S_DIM + q0 + quad * 4) * S_DIM + key;
        int mk0 = mp[0], mk1 = mp[S_DIM], mk2 = mp[2 * S_DIM], mk3 = mp[3 * S_DIM];
        floatx4 acc = {0.f, 0.f, 0.f, 0.f};
        #pragma unroll
        for (int s = 0; s < 2; ++s) {
            const float* kp = k + kvbase + (size_t)key * D_DIM + s * 32 + quad * 8;
            float4 k0 = *(const float4*)kp;
            float4 k1 = *(const float4*)(kp + 4);
            float kf[8] = {k0.x, k0.y, k0.z, k0.w, k1.x, k1.y, k1.z, k1.w};
            union { __hip_bfloat162 h[4]; short8 v; } BH, BL;
            #pragma unroll
            for (int p = 0; p < 4; ++p) {
                float x0 = kf[2 * p], x1 = kf[2 * p + 1];
                __hip_bfloat162 h2 = __float22bfloat162_rn(float2{x0, x1});
                BH.h[p] = h2;
                BL.h[p] = __float22bfloat162_rn(
                    float2{x0 - __bfloat162float(h2.x), x1 - __bfloat162float(h2.y)});
            }
            acc = __builtin_amdgcn_mfma_f32_16x16x32_bf16(ahi[s], BH.v, acc, 0, 0, 0);
            acc = __builtin_amdgcn_mfma_f32_16x16x32_bf16(ahi[s], BL.v, acc, 0, 0, 0);
            acc = __builtin_amdgcn_mfma_f32_16x16x32_bf16(alo[s], BH.v, acc, 0, 0, 0);
        }
        sc[c][0] = mk0 ? -1e30f : acc[0] * 0.125f;
        sc[c][1] = mk1 ? -1e30f : acc[1] * 0.125f;
        sc[c][2] = mk2 ? -1e30f : acc[2] * 0.125f;
        sc[c][3] = mk3 ? -1e30f : acc[3] * 0.125f;
    }

    #pragma unroll
    for (int r = 0; r < 4; ++r) {
        float mx = sc[0][r];
        #pragma unroll
        for (int c = 1; c < 16; ++c) mx = fmaxf(mx, sc[c][r]);
        #pragma unroll
        for (int o = 1; o < 16; o <<= 1) mx = fmaxf(mx, __shfl_xor(mx, o, 64));
        if (n16 == 0) mxtab[w * 16 + quad * 4 + r] = mx;
    }
    __syncthreads();
    #pragma unroll
    for (int r = 0; r < 4; ++r) {
        float mf = -3e38f;
        #pragma unroll
        for (int w2 = 0; w2 < 8; ++w2) mf = fmaxf(mf, mxtab[w2 * 16 + quad * 4 + r]);
        float l = 0.f;
        #pragma unroll
        for (int c = 0; c < 16; ++c) {
            float e = __expf(sc[c][r] - mf);
            sc[c][r] = e;
            l += e;
        }
        #pragma unroll
        for (int o = 1; o < 16; o <<= 1) l += __shfl_xor(l, o, 64);
        if (n16 == 0) ltab[w * 16 + quad * 4 + r] = l;
    }
    __syncthreads();
    #pragma unroll
    for (int r = 0; r < 4; ++r) {
        float l = 0.f;
        #pragma unroll
        for (int w2 = 0; w2 < 8; ++w2) l += ltab[w2 * 16 + quad * 4 + r];
        float inv = 1.0f / l;
        #pragma unroll
        for (int c = 0; c < 16; ++c) sc[c][r] *= inv;
    }

    {
        float* arow = attn + (size_t)(b * S_DIM + q0 + quad * 4) * S_DIM + key0 + n16;
        #pragma unroll
        for (int c = 0; c < 16; ++c) {
            #pragma unroll
            for (int r = 0; r < 4; ++r) arow[(size_t)r * S_DIM + c * 16] = sc[c][r];
        }
    }

    floatx4 o0 = {0,0,0,0}, o1 = {0,0,0,0}, o2 = {0,0,0,0}, o3 = {0,0,0,0};
    unsigned short* pw = pbuf + w * 576;
    #pragma unroll
    for (int s2 = 0; s2 < 8; ++s2) {
        #pragma unroll
        for (int h = 0; h < 2; ++h) {
            const int c = s2 * 2 + h;
            #pragma unroll
            for (int r = 0; r < 4; ++r)
                pw[(quad * 4 + r) * 36 + h * 16 + n16] = f2bf(sc[c][r]);
        }
        __syncthreads();
        short8 pa;
        {
            const uint32_t* pr = (const uint32_t*)((const char*)pbuf +
                                   (size_t)w * 1152 + n16 * 72 + quad * 16);
            union { uint32_t u[4]; short8 v; } P;
            P.u[0] = pr[0]; P.u[1] = pr[1]; P.u[2] = pr[2]; P.u[3] = pr[3];
            pa = P.v;
        }
        const size_t vrow0 = (size_t)(b * S_DIM + key0 + s2 * 32 + quad * 8) * D_DIM;
        #pragma unroll
        for (int nc = 0; nc < 4; ++nc) {
            const float* vp = v + vrow0 + nc * 16 + n16;
            union { __hip_bfloat162 h[4]; short8 v8; } BV;
            #pragma unroll
            for (int p = 0; p < 4; ++p) {
                float x0 = vp[(size_t)(2 * p) * D_DIM];
                float x1 = vp[(size_t)(2 * p + 1) * D_DIM];
                BV.h[p] = __float22bfloat162_rn(float2{x0, x1});
            }
            floatx4& oo = (nc == 0 ? o0 : nc == 1 ? o1 : nc == 2 ? o2 : o3);
            oo = __builtin_amdgcn_mfma_f32_16x16x32_bf16(pa, BV.v8, oo, 0, 0, 0);
        }
        __syncthreads();
    }

    #pragma unroll
    for (int nc = 0; nc < 4; ++nc) {
        floatx4 oo = (nc == 0 ? o0 : nc == 1 ? o1 : nc == 2 ? o2 : o3);
        #pragma unroll
        for (int i = 0; i < 4; ++i)
            obuf[(w * 16 + quad * 4 + i) * 68 + nc * 16 + n16] = oo[i];
    }
    __syncthreads();
    #pragma unroll
    for (int t2 = 0; t2 < 2; ++t2) {
        int idx = tid + t2 * 512;
        int m = idx >> 6, d = idx & 63;
        float a = 0.f;
        #pragma unroll
        for (int w2 = 0; w2 < 8; ++w2) a += obuf[(w2 * 16 + m) * 68 + d];
        out[(size_t)(b * S_DIM + q0 + m) * D_DIM + d] = a;
    }
}

extern "C" void kernel_launch(void* const* d_in, const int* in_sizes, int n_in,
                              void* d_out, int out_size, void* d_ws, size_t ws_size,
                              hipStream_t stream) {
    const float* q    = (const float*)d_in[0];
    const float* k    = (const float*)d_in[1];
    const float* v    = (const float*)d_in[2];
    const int*   mask = (const int*)d_in[3];

    float* out  = (float*)d_out;
    float* attn = out + (size_t)16 * S_DIM * D_DIM;   // 2,097,152 floats

    const size_t NE = (size_t)16 * S_DIM * D_DIM;     // 2,097,152 elements
    if (d_ws != nullptr && ws_size >= NE * 2 * 3) {
        unsigned short* khi = (unsigned short*)d_ws;
        unsigned short* klo = khi + NE;
        unsigned short* vtp = klo + NE;
        prep_k<<<dim3(2048), dim3(256), 0, stream>>>(k, khi, klo);
        prep_v<<<dim3(512),  dim3(256), 0, stream>>>(v, vtp);
        attn_fused_v2b<<<dim3(2048), dim3(512), 0, stream>>>(q, khi, klo, vtp, mask, out, attn);
    } else {
        attn_fused_v1<<<dim3(2048), dim3(512), 0, stream>>>(q, k, v, mask, out, attn);
    }
}

// Round 3
// 634.833 us; speedup vs baseline: 1.0104x; 1.0104x over previous
//
#include <hip/hip_runtime.h>
#include <hip/hip_bf16.h>
#include <stdint.h>

// B=16, S=2048, D=64. All fp32 I/O; mask int32 (nonzero == masked -> -1e30).
// d_in: q[B,S,D] f32, k[B,S,D] f32, v[B,S,D] f32, mask[B,S,S] i32
// d_out: output[B,S,D] f32 (2097152 floats) then attn[B,S,S] f32.
//
// v3 path (needs 20 MB workspace):
//   prep_mask: mask i32 -> bitmask (1 bit/elem) via __ballot   [8.4 MB]
//   prep_k2:   K f32 -> k_hi,k_lo bf16 in MFMA-fragment order  [coalesced loads]
//   prep_v2:   V f32 -> bf16 in PV B-fragment order            [coalesced loads]
//   attn_fused_v3: Phase B has zero mask loads (bits prefetched as 8B/lane,
//   applied via shfl+bfe); all K/V fragment loads are 16B/lane fully
//   coalesced; Phase E has NO barriers (wave-private pbuf; TBAA fixed with
//   may_alias so compiler keeps ds_write->ds_read order).
// Fallback: proven v1 kernel if ws too small.

#define S_DIM 2048
#define D_DIM 64

typedef short short8 __attribute__((ext_vector_type(8)));
typedef float floatx4 __attribute__((ext_vector_type(4)));
typedef unsigned short ushort8v __attribute__((ext_vector_type(8)));
typedef uint32_t u32a __attribute__((may_alias));

__device__ __forceinline__ unsigned short f2bf(float x) {
    uint32_t u = __float_as_uint(x);
    u += 0x7fffu + ((u >> 16) & 1u);
    return (unsigned short)(u >> 16);
}
__device__ __forceinline__ float bf2f(unsigned short h) {
    return __uint_as_float((uint32_t)h << 16);
}

// ---------------------------------------------------------------------------
// mask[B*S*S] i32 -> bits (1 bit per element, dword d holds elems [d*32,d*32+32))
__global__ __launch_bounds__(256) void prep_mask(
    const int* __restrict__ mask, uint32_t* __restrict__ bits)
{
    size_t i = (size_t)blockIdx.x * 256 + threadIdx.x;
    int m = mask[i];
    unsigned long long bal = __ballot(m != 0);
    int lane = threadIdx.x & 63;
    if ((lane & 31) == 0)
        bits[i >> 5] = (uint32_t)(bal >> ((lane >> 5) * 32));
}

// ---------------------------------------------------------------------------
// K -> hi/lo bf16 in fragment order:
// khi2[b][kc<128][s<2][quad<4][n16<16][e<8] = hi(K[b][kc*16+n16][s*32+quad*8+e])
// grid 16*128 blocks, 128 threads (t = s*64 + quad*16 + n16).
__global__ __launch_bounds__(128) void prep_k2(
    const float* __restrict__ k,
    unsigned short* __restrict__ khi2, unsigned short* __restrict__ klo2)
{
    const int b  = blockIdx.x >> 7;
    const int kc = blockIdx.x & 127;
    const int t  = threadIdx.x;
    const int s = t >> 6, quad = (t >> 4) & 3, n16 = t & 15;
    const float* src = k + ((size_t)(b * S_DIM) + kc * 16 + n16) * D_DIM + s * 32 + quad * 8;
    float4 x0 = *(const float4*)src;
    float4 x1 = *(const float4*)(src + 4);
    float xs[8] = {x0.x, x0.y, x0.z, x0.w, x1.x, x1.y, x1.z, x1.w};
    ushort8v h, l;
    #pragma unroll
    for (int e = 0; e < 8; ++e) {
        unsigned short hp = f2bf(xs[e]);
        h[e] = hp;
        l[e] = f2bf(xs[e] - bf2f(hp));
    }
    size_t o = ((size_t)(b * 128 + kc)) * 1024 + (size_t)t * 8;
    *(ushort8v*)(khi2 + o) = h;
    *(ushort8v*)(klo2 + o) = l;
}

// ---------------------------------------------------------------------------
// V -> bf16 in PV B-fragment order:
// vfrag[b][kb<64][nc<4][quad<4][n16<16][e<8] = bf16(V[b][kb*32+quad*8+e][nc*16+n16])
// grid 16*64 blocks, 256 threads (t = nc*64 + quad*16 + n16).
__global__ __launch_bounds__(256) void prep_v2(
    const float* __restrict__ v, unsigned short* __restrict__ vfrag)
{
    const int b  = blockIdx.x >> 6;
    const int kb = blockIdx.x & 63;
    const int t  = threadIdx.x;
    const int nc = t >> 6, quad = (t >> 4) & 3, n16 = t & 15;
    ushort8v o;
    #pragma unroll
    for (int e = 0; e < 8; ++e) {
        float x = v[((size_t)(b * S_DIM) + kb * 32 + quad * 8 + e) * D_DIM + nc * 16 + n16];
        o[e] = f2bf(x);
    }
    *(ushort8v*)(vfrag + ((size_t)(b * 64 + kb)) * 2048 + (size_t)t * 8) = o;
}

// ---------------------------------------------------------------------------
// Main kernel v3.
__global__ __launch_bounds__(512) void attn_fused_v3(
    const float* __restrict__ q,
    const unsigned short* __restrict__ khi2, const unsigned short* __restrict__ klo2,
    const unsigned short* __restrict__ vfrag,
    const uint32_t* __restrict__ bits,
    float* __restrict__ out, float* __restrict__ attn)
{
    __shared__ __align__(16) float qlds[16 * 68];              // 4.4 KB
    __shared__ __align__(16) unsigned short pbuf[8 * 16 * 36]; // 9.2 KB (wave-private)
    __shared__ __align__(16) float obuf[8 * 16 * 68];          // 34.8 KB
    __shared__ float mxtab[8 * 16];
    __shared__ float ltab[8 * 16];

    const int tid  = threadIdx.x;
    const int w    = tid >> 6;
    const int lane = tid & 63;
    const int quad = lane >> 4;
    const int n16  = lane & 15;
    const int b    = blockIdx.x >> 7;     // 128 q-tiles per batch
    const int q0   = (blockIdx.x & 127) * 16;
    const int key0 = w * 256;

    // ---------------- bits prefetch: 8B per lane, consumed after MFMA loop -
    // Wave w needs rows q0..q0+15, dwords [w*8, w*8+8) of its batch's bitmask.
    // Lane l holds flat indices {2l, 2l+1} of that 128-dword set
    // (flat = relrow*8 + dw  ->  relrow = l>>2, dw = 2*(l&3)).
    uint32_t blo, bhi;
    {
        const uint32_t* bsrc = bits +
            ((size_t)(b * S_DIM) + q0 + (lane >> 2)) * 64 + w * 8 + 2 * (lane & 3);
        uint2 bt = *(const uint2*)bsrc;
        blo = bt.x; bhi = bt.y;
    }

    // ---------------- Phase A: Q tile -> LDS, build A-frags (hi/lo) -------
    {
        int m = tid >> 5, d = (tid & 31) * 2;
        float2 qv = *(const float2*)(q + ((size_t)(b * S_DIM + q0 + m)) * D_DIM + d);
        qlds[m * 68 + d]     = qv.x;
        qlds[m * 68 + d + 1] = qv.y;
    }
    __syncthreads();

    short8 ahi[2], alo[2];
    #pragma unroll
    for (int s = 0; s < 2; ++s) {
        const float* qp = &qlds[n16 * 68 + s * 32 + quad * 8];
        union { unsigned short u[8]; short8 v; } H, L;
        #pragma unroll
        for (int p = 0; p < 8; ++p) {
            float x = qp[p];
            unsigned short hp = f2bf(x);
            H.u[p] = hp;
            L.u[p] = f2bf(x - bf2f(hp));
        }
        ahi[s] = H.v; alo[s] = L.v;
    }

    // ---------------- Phase B: scores = QK^T (frag-order K, coalesced) ----
    floatx4 sc[16];
    const unsigned short* khb = khi2 + (size_t)b * 131072;
    const unsigned short* klb = klo2 + (size_t)b * 131072;
    #pragma unroll
    for (int c = 0; c < 16; ++c) {
        const int kc = w * 16 + c;
        floatx4 acc = {0.f, 0.f, 0.f, 0.f};
        #pragma unroll
        for (int s = 0; s < 2; ++s) {
            const size_t off = (size_t)((kc * 2 + s) * 4 + quad) * 128 + n16 * 8;
            short8 BH = *(const short8*)(khb + off);
            short8 BL = *(const short8*)(klb + off);
            acc = __builtin_amdgcn_mfma_f32_16x16x32_bf16(ahi[s], BH, acc, 0, 0, 0);
            acc = __builtin_amdgcn_mfma_f32_16x16x32_bf16(ahi[s], BL, acc, 0, 0, 0);
            acc = __builtin_amdgcn_mfma_f32_16x16x32_bf16(alo[s], BH, acc, 0, 0, 0);
        }
        sc[c] = acc;
    }
    // mask + scale via in-register bitmask (shfl redistribution)
    #pragma unroll
    for (int r = 0; r < 4; ++r) {
        #pragma unroll
        for (int c = 0; c < 16; ++c) {
            int srcl = quad * 16 + r * 4 + (c >> 2);
            uint32_t d = (uint32_t)__shfl((int)((c & 2) ? bhi : blo), srcl, 64);
            uint32_t bit = (d >> ((c & 1) * 16 + n16)) & 1u;
            sc[c][r] = bit ? -1e30f : sc[c][r] * 0.125f;
        }
    }

    // ---------------- Phase C: exact softmax over 2048 keys ---------------
    #pragma unroll
    for (int r = 0; r < 4; ++r) {
        float mx = sc[0][r];
        #pragma unroll
        for (int c = 1; c < 16; ++c) mx = fmaxf(mx, sc[c][r]);
        #pragma unroll
        for (int o = 1; o < 16; o <<= 1) mx = fmaxf(mx, __shfl_xor(mx, o, 64));
        if (n16 == 0) mxtab[w * 16 + quad * 4 + r] = mx;
    }
    __syncthreads();
    #pragma unroll
    for (int r = 0; r < 4; ++r) {
        float mf = -3e38f;
        #pragma unroll
        for (int w2 = 0; w2 < 8; ++w2) mf = fmaxf(mf, mxtab[w2 * 16 + quad * 4 + r]);
        float l = 0.f;
        #pragma unroll
        for (int c = 0; c < 16; ++c) {
            float e = __expf(sc[c][r] - mf);
            sc[c][r] = e;
            l += e;
        }
        #pragma unroll
        for (int o = 1; o < 16; o <<= 1) l += __shfl_xor(l, o, 64);
        if (n16 == 0) ltab[w * 16 + quad * 4 + r] = l;
    }
    __syncthreads();
    #pragma unroll
    for (int r = 0; r < 4; ++r) {
        float l = 0.f;
        #pragma unroll
        for (int w2 = 0; w2 < 8; ++w2) l += ltab[w2 * 16 + quad * 4 + r];
        float inv = 1.0f / l;
        #pragma unroll
        for (int c = 0; c < 16; ++c) sc[c][r] *= inv;
    }

    // ---------------- Phase D: write attn (fp32, 64B-coalesced/quad) ------
    {
        float* arow = attn + (size_t)(b * S_DIM + q0 + quad * 4) * S_DIM + key0 + n16;
        #pragma unroll
        for (int c = 0; c < 16; ++c) {
            #pragma unroll
            for (int r = 0; r < 4; ++r) arow[(size_t)r * S_DIM + c * 16] = sc[c][r];
        }
    }

    // ---------------- Phase E: O += P*V, NO barriers (wave-private pbuf) --
    // P-transpose reads use may_alias u32 so the compiler keeps the
    // ds_write(u16) -> ds_read(u32) dependency ordered (this was the Round-1
    // NaN: TBAA said no-alias and the reads were hoisted above the writes).
    floatx4 o0 = {0,0,0,0}, o1 = {0,0,0,0}, o2 = {0,0,0,0}, o3 = {0,0,0,0};
    unsigned short* pw = pbuf + w * 576;   // 16 rows x 36 (32 keys + pad)
    const unsigned short* vtb = vfrag + (size_t)b * 131072;
    #pragma unroll
    for (int s2 = 0; s2 < 8; ++s2) {
        #pragma unroll
        for (int h = 0; h < 2; ++h) {
            const int c = s2 * 2 + h;
            #pragma unroll
            for (int r = 0; r < 4; ++r)
                pw[(quad * 4 + r) * 36 + h * 16 + n16] = f2bf(sc[c][r]);
        }
        short8 pa;
        {
            const u32a* pr = (const u32a*)((const char*)pbuf +
                                   (size_t)w * 1152 + n16 * 72 + quad * 16);
            union { uint32_t u[4]; short8 v; } P;
            P.u[0] = pr[0]; P.u[1] = pr[1]; P.u[2] = pr[2]; P.u[3] = pr[3];
            pa = P.v;
        }
        const int kb = w * 8 + s2;
        #pragma unroll
        for (int nc = 0; nc < 4; ++nc) {
            const size_t off = (size_t)((kb * 4 + nc) * 4 + quad) * 128 + n16 * 8;
            short8 bv = *(const short8*)(vtb + off);
            floatx4& oo = (nc == 0 ? o0 : nc == 1 ? o1 : nc == 2 ? o2 : o3);
            oo = __builtin_amdgcn_mfma_f32_16x16x32_bf16(pa, bv, oo, 0, 0, 0);
        }
    }

    // ---------------- Phase F: reduce per-wave partial O, store -----------
    #pragma unroll
    for (int nc = 0; nc < 4; ++nc) {
        floatx4 oo = (nc == 0 ? o0 : nc == 1 ? o1 : nc == 2 ? o2 : o3);
        #pragma unroll
        for (int i = 0; i < 4; ++i)
            obuf[(w * 16 + quad * 4 + i) * 68 + nc * 16 + n16] = oo[i];
    }
    __syncthreads();
    #pragma unroll
    for (int t2 = 0; t2 < 2; ++t2) {
        int idx = tid + t2 * 512;
        int m = idx >> 6, d = idx & 63;
        float a = 0.f;
        #pragma unroll
        for (int w2 = 0; w2 < 8; ++w2) a += obuf[(w2 * 16 + m) * 68 + d];
        out[(size_t)(b * S_DIM + q0 + m) * D_DIM + d] = a;
    }
}

// ---------------------------------------------------------------------------
// Fallback v1 (proven) — used only if workspace is too small.
__global__ __launch_bounds__(512) void attn_fused_v1(
    const float* __restrict__ q, const float* __restrict__ k,
    const float* __restrict__ v, const int* __restrict__ mask,
    float* __restrict__ out, float* __restrict__ attn)
{
    __shared__ __align__(16) float qlds[16 * 68];
    __shared__ __align__(16) unsigned short pbuf[8 * 16 * 36];
    __shared__ __align__(16) float obuf[8 * 16 * 68];
    __shared__ float mxtab[8 * 16];
    __shared__ float ltab[8 * 16];

    const int tid  = threadIdx.x;
    const int w    = tid >> 6;
    const int lane = tid & 63;
    const int quad = lane >> 4;
    const int n16  = lane & 15;
    const int b    = blockIdx.x >> 7;
    const int q0   = (blockIdx.x & 127) * 16;
    const int key0 = w * 256;

    {
        int m = tid >> 5, d = (tid & 31) * 2;
        float2 qv = *(const float2*)(q + ((size_t)(b * S_DIM + q0 + m)) * D_DIM + d);
        qlds[m * 68 + d]     = qv.x;
        qlds[m * 68 + d + 1] = qv.y;
    }
    __syncthreads();

    short8 ahi[2], alo[2];
    #pragma unroll
    for (int s = 0; s < 2; ++s) {
        const float* qp = &qlds[n16 * 68 + s * 32 + quad * 8];
        union { __hip_bfloat162 h[4]; short8 v; } H, L;
        #pragma unroll
        for (int p = 0; p < 4; ++p) {
            float x0 = qp[2 * p], x1 = qp[2 * p + 1];
            __hip_bfloat162 h2 = __float22bfloat162_rn(float2{x0, x1});
            float l0 = x0 - __bfloat162float(h2.x);
            float l1 = x1 - __bfloat162float(h2.y);
            H.h[p] = h2;
            L.h[p] = __float22bfloat162_rn(float2{l0, l1});
        }
        ahi[s] = H.v; alo[s] = L.v;
    }

    floatx4 sc[16];
    const size_t kvbase = (size_t)(b * S_DIM) * D_DIM;
    #pragma unroll
    for (int c = 0; c < 16; ++c) {
        const int key = key0 + c * 16 + n16;
        const int* mp = mask + (size_t)(b * S_DIM + q0 + quad * 4) * S_DIM + key;
        int mk0 = mp[0], mk1 = mp[S_DIM], mk2 = mp[2 * S_DIM], mk3 = mp[3 * S_DIM];
        floatx4 acc = {0.f, 0.f, 0.f, 0.f};
        #pragma unroll
        for (int s = 0; s < 2; ++s) {
            const float* kp = k + kvbase + (size_t)key * D_DIM + s * 32 + quad * 8;
            float4 k0 = *(const float4*)kp;
            float4 k1 = *(const float4*)(kp + 4);
            float kf[8] = {k0.x, k0.y, k0.z, k0.w, k1.x, k1.y, k1.z, k1.w};
            union { __hip_bfloat162 h[4]; short8 v; } BH, BL;
            #pragma unroll
            for (int p = 0; p < 4; ++p) {
                float x0 = kf[2 * p], x1 = kf[2 * p + 1];
                __hip_bfloat162 h2 = __float22bfloat162_rn(float2{x0, x1});
                BH.h[p] = h2;
                BL.h[p] = __float22bfloat162_rn(
                    float2{x0 - __bfloat162float(h2.x), x1 - __bfloat162float(h2.y)});
            }
            acc = __builtin_amdgcn_mfma_f32_16x16x32_bf16(ahi[s], BH.v, acc, 0, 0, 0);
            acc = __builtin_amdgcn_mfma_f32_16x16x32_bf16(ahi[s], BL.v, acc, 0, 0, 0);
            acc = __builtin_amdgcn_mfma_f32_16x16x32_bf16(alo[s], BH.v, acc, 0, 0, 0);
        }
        sc[c][0] = mk0 ? -1e30f : acc[0] * 0.125f;
        sc[c][1] = mk1 ? -1e30f : acc[1] * 0.125f;
        sc[c][2] = mk2 ? -1e30f : acc[2] * 0.125f;
        sc[c][3] = mk3 ? -1e30f : acc[3] * 0.125f;
    }

    #pragma unroll
    for (int r = 0; r < 4; ++r) {
        float mx = sc[0][r];
        #pragma unroll
        for (int c = 1; c < 16; ++c) mx = fmaxf(mx, sc[c][r]);
        #pragma unroll
        for (int o = 1; o < 16; o <<= 1) mx = fmaxf(mx, __shfl_xor(mx, o, 64));
        if (n16 == 0) mxtab[w * 16 + quad * 4 + r] = mx;
    }
    __syncthreads();
    #pragma unroll
    for (int r = 0; r < 4; ++r) {
        float mf = -3e38f;
        #pragma unroll
        for (int w2 = 0; w2 < 8; ++w2) mf = fmaxf(mf, mxtab[w2 * 16 + quad * 4 + r]);
        float l = 0.f;
        #pragma unroll
        for (int c = 0; c < 16; ++c) {
            float e = __expf(sc[c][r] - mf);
            sc[c][r] = e;
            l += e;
        }
        #pragma unroll
        for (int o = 1; o < 16; o <<= 1) l += __shfl_xor(l, o, 64);
        if (n16 == 0) ltab[w * 16 + quad * 4 + r] = l;
    }
    __syncthreads();
    #pragma unroll
    for (int r = 0; r < 4; ++r) {
        float l = 0.f;
        #pragma unroll
        for (int w2 = 0; w2 < 8; ++w2) l += ltab[w2 * 16 + quad * 4 + r];
        float inv = 1.0f / l;
        #pragma unroll
        for (int c = 0; c < 16; ++c) sc[c][r] *= inv;
    }

    {
        float* arow = attn + (size_t)(b * S_DIM + q0 + quad * 4) * S_DIM + key0 + n16;
        #pragma unroll
        for (int c = 0; c < 16; ++c) {
            #pragma unroll
            for (int r = 0; r < 4; ++r) arow[(size_t)r * S_DIM + c * 16] = sc[c][r];
        }
    }

    floatx4 o0 = {0,0,0,0}, o1 = {0,0,0,0}, o2 = {0,0,0,0}, o3 = {0,0,0,0};
    unsigned short* pw = pbuf + w * 576;
    #pragma unroll
    for (int s2 = 0; s2 < 8; ++s2) {
        #pragma unroll
        for (int h = 0; h < 2; ++h) {
            const int c = s2 * 2 + h;
            #pragma unroll
            for (int r = 0; r < 4; ++r)
                pw[(quad * 4 + r) * 36 + h * 16 + n16] = f2bf(sc[c][r]);
        }
        __syncthreads();
        short8 pa;
        {
            const uint32_t* pr = (const uint32_t*)((const char*)pbuf +
                                   (size_t)w * 1152 + n16 * 72 + quad * 16);
            union { uint32_t u[4]; short8 v; } P;
            P.u[0] = pr[0]; P.u[1] = pr[1]; P.u[2] = pr[2]; P.u[3] = pr[3];
            pa = P.v;
        }
        const size_t vrow0 = (size_t)(b * S_DIM + key0 + s2 * 32 + quad * 8) * D_DIM;
        #pragma unroll
        for (int nc = 0; nc < 4; ++nc) {
            const float* vp = v + vrow0 + nc * 16 + n16;
            union { __hip_bfloat162 h[4]; short8 v8; } BV;
            #pragma unroll
            for (int p = 0; p < 4; ++p) {
                float x0 = vp[(size_t)(2 * p) * D_DIM];
                float x1 = vp[(size_t)(2 * p + 1) * D_DIM];
                BV.h[p] = __float22bfloat162_rn(float2{x0, x1});
            }
            floatx4& oo = (nc == 0 ? o0 : nc == 1 ? o1 : nc == 2 ? o2 : o3);
            oo = __builtin_amdgcn_mfma_f32_16x16x32_bf16(pa, BV.v8, oo, 0, 0, 0);
        }
        __syncthreads();
    }

    #pragma unroll
    for (int nc = 0; nc < 4; ++nc) {
        floatx4 oo = (nc == 0 ? o0 : nc == 1 ? o1 : nc == 2 ? o2 : o3);
        #pragma unroll
        for (int i = 0; i < 4; ++i)
            obuf[(w * 16 + quad * 4 + i) * 68 + nc * 16 + n16] = oo[i];
    }
    __syncthreads();
    #pragma unroll
    for (int t2 = 0; t2 < 2; ++t2) {
        int idx = tid + t2 * 512;
        int m = idx >> 6, d = idx & 63;
        float a = 0.f;
        #pragma unroll
        for (int w2 = 0; w2 < 8; ++w2) a += obuf[(w2 * 16 + m) * 68 + d];
        out[(size_t)(b * S_DIM + q0 + m) * D_DIM + d] = a;
    }
}

extern "C" void kernel_launch(void* const* d_in, const int* in_sizes, int n_in,
                              void* d_out, int out_size, void* d_ws, size_t ws_size,
                              hipStream_t stream) {
    const float* q    = (const float*)d_in[0];
    const float* k    = (const float*)d_in[1];
    const float* v    = (const float*)d_in[2];
    const int*   mask = (const int*)d_in[3];

    float* out  = (float*)d_out;
    float* attn = out + (size_t)16 * S_DIM * D_DIM;   // 2,097,152 floats

    const size_t NE = (size_t)16 * S_DIM * D_DIM;     // 2,097,152 elements
    const size_t need = NE * 2 * 3 + NE * 4;          // khi2+klo2+vfrag (bf16) + bits (u32) = 20 MB
    if (d_ws != nullptr && ws_size >= need) {
        unsigned short* khi2  = (unsigned short*)d_ws;
        unsigned short* klo2  = khi2 + NE;
        unsigned short* vfrag = klo2 + NE;
        uint32_t*       bits  = (uint32_t*)(vfrag + NE);
        prep_mask<<<dim3(262144), dim3(256), 0, stream>>>(mask, bits);
        prep_k2<<<dim3(2048), dim3(128), 0, stream>>>(k, khi2, klo2);
        prep_v2<<<dim3(1024), dim3(256), 0, stream>>>(v, vfrag);
        attn_fused_v3<<<dim3(2048), dim3(512), 0, stream>>>(q, khi2, klo2, vfrag, bits, out, attn);
    } else {
        attn_fused_v1<<<dim3(2048), dim3(512), 0, stream>>>(q, k, v, mask, out, attn);
    }
}

// Round 4
// 580.162 us; speedup vs baseline: 1.1056x; 1.0942x over previous
//
#include <hip/hip_runtime.h>
#include <hip/hip_bf16.h>
#include <stdint.h>

// B=16, S=2048, D=64. All fp32 I/O; mask int32 (nonzero == masked -> -1e30).
// d_in: q[B,S,D] f32, k[B,S,D] f32, v[B,S,D] f32, mask[B,S,S] i32
// d_out: output[B,S,D] f32 (2097152 floats) then attn[B,S,S] f32.
//
// v4 path (needs 20 MB workspace):
//   prep_all (ONE kernel, 3 block-ranges):
//     [0,8192):     mask i32 -> bitmask, 32 elems/thread, coalesced + ballot
//     [8192,9216):  K f32 -> k_hi,k_lo bf16 in MFMA-fragment order
//     [9216,10240): V f32 -> bf16 in PV B-fragment order
//   attn_fused_v4: = proven v3 + nontemporal attn stores.
// Fallback: proven v1 kernel if ws too small.

#define S_DIM 2048
#define D_DIM 64

typedef short short8 __attribute__((ext_vector_type(8)));
typedef float floatx4 __attribute__((ext_vector_type(4)));
typedef unsigned short ushort8v __attribute__((ext_vector_type(8)));
typedef uint32_t u32a __attribute__((may_alias));

__device__ __forceinline__ unsigned short f2bf(float x) {
    uint32_t u = __float_as_uint(x);
    u += 0x7fffu + ((u >> 16) & 1u);
    return (unsigned short)(u >> 16);
}
__device__ __forceinline__ float bf2f(unsigned short h) {
    return __uint_as_float((uint32_t)h << 16);
}

// ---------------------------------------------------------------------------
// Fused prep. Grid 10240 x 256.
//  mask part: per block 8192 elems; thread j-loop of 32 coalesced dword loads,
//  one ballot per 64 elems -> bits dword d holds elems [d*32, d*32+32).
//  k part: khi2[b][kc<128][(s,quad,n16)<128][e<8] = hi(K[b][kc*16+n16][s*32+quad*8+e])
//  v part: vfrag[b][kb<64][(nc,quad,n16)<256][e<8] = bf16(V[b][kb*32+quad*8+e][nc*16+n16])
__global__ __launch_bounds__(256) void prep_all(
    const int* __restrict__ mask, uint32_t* __restrict__ bits,
    const float* __restrict__ k,
    unsigned short* __restrict__ khi2, unsigned short* __restrict__ klo2,
    const float* __restrict__ v, unsigned short* __restrict__ vfrag)
{
    const int blk = blockIdx.x;
    const int tid = threadIdx.x;

    if (blk < 8192) {
        // ---- mask -> bits ----
        const size_t base = (size_t)blk * 8192;
        const int lane = tid & 63;
        const size_t wbase = base + (size_t)(tid & ~63);
        #pragma unroll
        for (int j = 0; j < 32; ++j) {
            int m = mask[base + j * 256 + tid];
            unsigned long long bal = __ballot(m != 0);
            if ((lane & 31) == 0) {
                size_t wb = wbase + j * 256;            // multiple of 64
                bits[(wb >> 5) + (lane >> 5)] = (uint32_t)(bal >> ((lane >> 5) * 32));
            }
        }
    } else if (blk < 9216) {
        // ---- K -> hi/lo fragment order (2 kc per block) ----
        const int e  = blk - 8192;          // 0..1023
        const int b  = e >> 6;              // 64 blocks per batch
        const int kc = (e & 63) * 2 + (tid >> 7);
        const int t  = tid & 127;
        const int s = t >> 6, quad = (t >> 4) & 3, n16 = t & 15;
        const float* src = k + ((size_t)(b * S_DIM) + kc * 16 + n16) * D_DIM + s * 32 + quad * 8;
        float4 x0 = *(const float4*)src;
        float4 x1 = *(const float4*)(src + 4);
        float xs[8] = {x0.x, x0.y, x0.z, x0.w, x1.x, x1.y, x1.z, x1.w};
        ushort8v h, l;
        #pragma unroll
        for (int p = 0; p < 8; ++p) {
            unsigned short hp = f2bf(xs[p]);
            h[p] = hp;
            l[p] = f2bf(xs[p] - bf2f(hp));
        }
        size_t o = ((size_t)(b * 128 + kc)) * 1024 + (size_t)t * 8;
        *(ushort8v*)(khi2 + o) = h;
        *(ushort8v*)(klo2 + o) = l;
    } else {
        // ---- V -> PV fragment order ----
        const int e  = blk - 9216;          // 0..1023
        const int b  = e >> 6;
        const int kb = e & 63;
        const int nc = tid >> 6, quad = (tid >> 4) & 3, n16 = tid & 15;
        ushort8v o;
        #pragma unroll
        for (int p = 0; p < 8; ++p) {
            float x = v[((size_t)(b * S_DIM) + kb * 32 + quad * 8 + p) * D_DIM + nc * 16 + n16];
            o[p] = f2bf(x);
        }
        *(ushort8v*)(vfrag + ((size_t)(b * 64 + kb)) * 2048 + (size_t)tid * 8) = o;
    }
}

// ---------------------------------------------------------------------------
// Main kernel v4 (= proven v3 + nontemporal attn stores).
__global__ __launch_bounds__(512) void attn_fused_v4(
    const float* __restrict__ q,
    const unsigned short* __restrict__ khi2, const unsigned short* __restrict__ klo2,
    const unsigned short* __restrict__ vfrag,
    const uint32_t* __restrict__ bits,
    float* __restrict__ out, float* __restrict__ attn)
{
    __shared__ __align__(16) float qlds[16 * 68];              // 4.4 KB
    __shared__ __align__(16) unsigned short pbuf[8 * 16 * 36]; // 9.2 KB (wave-private)
    __shared__ __align__(16) float obuf[8 * 16 * 68];          // 34.8 KB
    __shared__ float mxtab[8 * 16];
    __shared__ float ltab[8 * 16];

    const int tid  = threadIdx.x;
    const int w    = tid >> 6;
    const int lane = tid & 63;
    const int quad = lane >> 4;
    const int n16  = lane & 15;
    const int b    = blockIdx.x >> 7;     // 128 q-tiles per batch
    const int q0   = (blockIdx.x & 127) * 16;
    const int key0 = w * 256;

    // ---------------- bits prefetch: 8B per lane ---------------------------
    uint32_t blo, bhi;
    {
        const uint32_t* bsrc = bits +
            ((size_t)(b * S_DIM) + q0 + (lane >> 2)) * 64 + w * 8 + 2 * (lane & 3);
        uint2 bt = *(const uint2*)bsrc;
        blo = bt.x; bhi = bt.y;
    }

    // ---------------- Phase A: Q tile -> LDS, build A-frags (hi/lo) -------
    {
        int m = tid >> 5, d = (tid & 31) * 2;
        float2 qv = *(const float2*)(q + ((size_t)(b * S_DIM + q0 + m)) * D_DIM + d);
        qlds[m * 68 + d]     = qv.x;
        qlds[m * 68 + d + 1] = qv.y;
    }
    __syncthreads();

    short8 ahi[2], alo[2];
    #pragma unroll
    for (int s = 0; s < 2; ++s) {
        const float* qp = &qlds[n16 * 68 + s * 32 + quad * 8];
        union { unsigned short u[8]; short8 v; } H, L;
        #pragma unroll
        for (int p = 0; p < 8; ++p) {
            float x = qp[p];
            unsigned short hp = f2bf(x);
            H.u[p] = hp;
            L.u[p] = f2bf(x - bf2f(hp));
        }
        ahi[s] = H.v; alo[s] = L.v;
    }

    // ---------------- Phase B: scores = QK^T (frag-order K, coalesced) ----
    floatx4 sc[16];
    const unsigned short* khb = khi2 + (size_t)b * 131072;
    const unsigned short* klb = klo2 + (size_t)b * 131072;
    #pragma unroll
    for (int c = 0; c < 16; ++c) {
        const int kc = w * 16 + c;
        floatx4 acc = {0.f, 0.f, 0.f, 0.f};
        #pragma unroll
        for (int s = 0; s < 2; ++s) {
            const size_t off = (size_t)((kc * 2 + s) * 4 + quad) * 128 + n16 * 8;
            short8 BH = *(const short8*)(khb + off);
            short8 BL = *(const short8*)(klb + off);
            acc = __builtin_amdgcn_mfma_f32_16x16x32_bf16(ahi[s], BH, acc, 0, 0, 0);
            acc = __builtin_amdgcn_mfma_f32_16x16x32_bf16(ahi[s], BL, acc, 0, 0, 0);
            acc = __builtin_amdgcn_mfma_f32_16x16x32_bf16(alo[s], BH, acc, 0, 0, 0);
        }
        sc[c] = acc;
    }
    // mask + scale via in-register bitmask (shfl redistribution)
    #pragma unroll
    for (int r = 0; r < 4; ++r) {
        #pragma unroll
        for (int c = 0; c < 16; ++c) {
            int srcl = quad * 16 + r * 4 + (c >> 2);
            uint32_t d = (uint32_t)__shfl((int)((c & 2) ? bhi : blo), srcl, 64);
            uint32_t bit = (d >> ((c & 1) * 16 + n16)) & 1u;
            sc[c][r] = bit ? -1e30f : sc[c][r] * 0.125f;
        }
    }

    // ---------------- Phase C: exact softmax over 2048 keys ---------------
    #pragma unroll
    for (int r = 0; r < 4; ++r) {
        float mx = sc[0][r];
        #pragma unroll
        for (int c = 1; c < 16; ++c) mx = fmaxf(mx, sc[c][r]);
        #pragma unroll
        for (int o = 1; o < 16; o <<= 1) mx = fmaxf(mx, __shfl_xor(mx, o, 64));
        if (n16 == 0) mxtab[w * 16 + quad * 4 + r] = mx;
    }
    __syncthreads();
    #pragma unroll
    for (int r = 0; r < 4; ++r) {
        float mf = -3e38f;
        #pragma unroll
        for (int w2 = 0; w2 < 8; ++w2) mf = fmaxf(mf, mxtab[w2 * 16 + quad * 4 + r]);
        float l = 0.f;
        #pragma unroll
        for (int c = 0; c < 16; ++c) {
            float e = __expf(sc[c][r] - mf);
            sc[c][r] = e;
            l += e;
        }
        #pragma unroll
        for (int o = 1; o < 16; o <<= 1) l += __shfl_xor(l, o, 64);
        if (n16 == 0) ltab[w * 16 + quad * 4 + r] = l;
    }
    __syncthreads();
    #pragma unroll
    for (int r = 0; r < 4; ++r) {
        float l = 0.f;
        #pragma unroll
        for (int w2 = 0; w2 < 8; ++w2) l += ltab[w2 * 16 + quad * 4 + r];
        float inv = 1.0f / l;
        #pragma unroll
        for (int c = 0; c < 16; ++c) sc[c][r] *= inv;
    }

    // ---------------- Phase D: write attn (fp32, nontemporal) -------------
    {
        float* arow = attn + (size_t)(b * S_DIM + q0 + quad * 4) * S_DIM + key0 + n16;
        #pragma unroll
        for (int c = 0; c < 16; ++c) {
            #pragma unroll
            for (int r = 0; r < 4; ++r)
                __builtin_nontemporal_store(sc[c][r], arow + (size_t)r * S_DIM + c * 16);
        }
    }

    // ---------------- Phase E: O += P*V, NO barriers (wave-private pbuf) --
    floatx4 o0 = {0,0,0,0}, o1 = {0,0,0,0}, o2 = {0,0,0,0}, o3 = {0,0,0,0};
    unsigned short* pw = pbuf + w * 576;   // 16 rows x 36 (32 keys + pad)
    const unsigned short* vtb = vfrag + (size_t)b * 131072;
    #pragma unroll
    for (int s2 = 0; s2 < 8; ++s2) {
        #pragma unroll
        for (int h = 0; h < 2; ++h) {
            const int c = s2 * 2 + h;
            #pragma unroll
            for (int r = 0; r < 4; ++r)
                pw[(quad * 4 + r) * 36 + h * 16 + n16] = f2bf(sc[c][r]);
        }
        short8 pa;
        {
            const u32a* pr = (const u32a*)((const char*)pbuf +
                                   (size_t)w * 1152 + n16 * 72 + quad * 16);
            union { uint32_t u[4]; short8 v; } P;
            P.u[0] = pr[0]; P.u[1] = pr[1]; P.u[2] = pr[2]; P.u[3] = pr[3];
            pa = P.v;
        }
        const int kb = w * 8 + s2;
        #pragma unroll
        for (int nc = 0; nc < 4; ++nc) {
            const size_t off = (size_t)((kb * 4 + nc) * 4 + quad) * 128 + n16 * 8;
            short8 bv = *(const short8*)(vtb + off);
            floatx4& oo = (nc == 0 ? o0 : nc == 1 ? o1 : nc == 2 ? o2 : o3);
            oo = __builtin_amdgcn_mfma_f32_16x16x32_bf16(pa, bv, oo, 0, 0, 0);
        }
    }

    // ---------------- Phase F: reduce per-wave partial O, store -----------
    #pragma unroll
    for (int nc = 0; nc < 4; ++nc) {
        floatx4 oo = (nc == 0 ? o0 : nc == 1 ? o1 : nc == 2 ? o2 : o3);
        #pragma unroll
        for (int i = 0; i < 4; ++i)
            obuf[(w * 16 + quad * 4 + i) * 68 + nc * 16 + n16] = oo[i];
    }
    __syncthreads();
    #pragma unroll
    for (int t2 = 0; t2 < 2; ++t2) {
        int idx = tid + t2 * 512;
        int m = idx >> 6, d = idx & 63;
        float a = 0.f;
        #pragma unroll
        for (int w2 = 0; w2 < 8; ++w2) a += obuf[(w2 * 16 + m) * 68 + d];
        out[(size_t)(b * S_DIM + q0 + m) * D_DIM + d] = a;
    }
}

// ---------------------------------------------------------------------------
// Fallback v1 (proven) — used only if workspace is too small.
__global__ __launch_bounds__(512) void attn_fused_v1(
    const float* __restrict__ q, const float* __restrict__ k,
    const float* __restrict__ v, const int* __restrict__ mask,
    float* __restrict__ out, float* __restrict__ attn)
{
    __shared__ __align__(16) float qlds[16 * 68];
    __shared__ __align__(16) unsigned short pbuf[8 * 16 * 36];
    __shared__ __align__(16) float obuf[8 * 16 * 68];
    __shared__ float mxtab[8 * 16];
    __shared__ float ltab[8 * 16];

    const int tid  = threadIdx.x;
    const int w    = tid >> 6;
    const int lane = tid & 63;
    const int quad = lane >> 4;
    const int n16  = lane & 15;
    const int b    = blockIdx.x >> 7;
    const int q0   = (blockIdx.x & 127) * 16;
    const int key0 = w * 256;

    {
        int m = tid >> 5, d = (tid & 31) * 2;
        float2 qv = *(const float2*)(q + ((size_t)(b * S_DIM + q0 + m)) * D_DIM + d);
        qlds[m * 68 + d]     = qv.x;
        qlds[m * 68 + d + 1] = qv.y;
    }
    __syncthreads();

    short8 ahi[2], alo[2];
    #pragma unroll
    for (int s = 0; s < 2; ++s) {
        const float* qp = &qlds[n16 * 68 + s * 32 + quad * 8];
        union { __hip_bfloat162 h[4]; short8 v; } H, L;
        #pragma unroll
        for (int p = 0; p < 4; ++p) {
            float x0 = qp[2 * p], x1 = qp[2 * p + 1];
            __hip_bfloat162 h2 = __float22bfloat162_rn(float2{x0, x1});
            float l0 = x0 - __bfloat162float(h2.x);
            float l1 = x1 - __bfloat162float(h2.y);
            H.h[p] = h2;
            L.h[p] = __float22bfloat162_rn(float2{l0, l1});
        }
        ahi[s] = H.v; alo[s] = L.v;
    }

    floatx4 sc[16];
    const size_t kvbase = (size_t)(b * S_DIM) * D_DIM;
    #pragma unroll
    for (int c = 0; c < 16; ++c) {
        const int key = key0 + c * 16 + n16;
        const int* mp = mask + (size_t)(b * S_DIM + q0 + quad * 4) * S_DIM + key;
        int mk0 = mp[0], mk1 = mp[S_DIM], mk2 = mp[2 * S_DIM], mk3 = mp[3 * S_DIM];
        floatx4 acc = {0.f, 0.f, 0.f, 0.f};
        #pragma unroll
        for (int s = 0; s < 2; ++s) {
            const float* kp = k + kvbase + (size_t)key * D_DIM + s * 32 + quad * 8;
            float4 k0 = *(const float4*)kp;
            float4 k1 = *(const float4*)(kp + 4);
            float kf[8] = {k0.x, k0.y, k0.z, k0.w, k1.x, k1.y, k1.z, k1.w};
            union { __hip_bfloat162 h[4]; short8 v; } BH, BL;
            #pragma unroll
            for (int p = 0; p < 4; ++p) {
                float x0 = kf[2 * p], x1 = kf[2 * p + 1];
                __hip_bfloat162 h2 = __float22bfloat162_rn(float2{x0, x1});
                BH.h[p] = h2;
                BL.h[p] = __float22bfloat162_rn(
                    float2{x0 - __bfloat162float(h2.x), x1 - __bfloat162float(h2.y)});
            }
            acc = __builtin_amdgcn_mfma_f32_16x16x32_bf16(ahi[s], BH.v, acc, 0, 0, 0);
            acc = __builtin_amdgcn_mfma_f32_16x16x32_bf16(ahi[s], BL.v, acc, 0, 0, 0);
            acc = __builtin_amdgcn_mfma_f32_16x16x32_bf16(alo[s], BH.v, acc, 0, 0, 0);
        }
        sc[c][0] = mk0 ? -1e30f : acc[0] * 0.125f;
        sc[c][1] = mk1 ? -1e30f : acc[1] * 0.125f;
        sc[c][2] = mk2 ? -1e30f : acc[2] * 0.125f;
        sc[c][3] = mk3 ? -1e30f : acc[3] * 0.125f;
    }

    #pragma unroll
    for (int r = 0; r < 4; ++r) {
        float mx = sc[0][r];
        #pragma unroll
        for (int c = 1; c < 16; ++c) mx = fmaxf(mx, sc[c][r]);
        #pragma unroll
        for (int o = 1; o < 16; o <<= 1) mx = fmaxf(mx, __shfl_xor(mx, o, 64));
        if (n16 == 0) mxtab[w * 16 + quad * 4 + r] = mx;
    }
    __syncthreads();
    #pragma unroll
    for (int r = 0; r < 4; ++r) {
        float mf = -3e38f;
        #pragma unroll
        for (int w2 = 0; w2 < 8; ++w2) mf = fmaxf(mf, mxtab[w2 * 16 + quad * 4 + r]);
        float l = 0.f;
        #pragma unroll
        for (int c = 0; c < 16; ++c) {
            float e = __expf(sc[c][r] - mf);
            sc[c][r] = e;
            l += e;
        }
        #pragma unroll
        for (int o = 1; o < 16; o <<= 1) l += __shfl_xor(l, o, 64);
        if (n16 == 0) ltab[w * 16 + quad * 4 + r] = l;
    }
    __syncthreads();
    #pragma unroll
    for (int r = 0; r < 4; ++r) {
        float l = 0.f;
        #pragma unroll
        for (int w2 = 0; w2 < 8; ++w2) l += ltab[w2 * 16 + quad * 4 + r];
        float inv = 1.0f / l;
        #pragma unroll
        for (int c = 0; c < 16; ++c) sc[c][r] *= inv;
    }

    {
        float* arow = attn + (size_t)(b * S_DIM + q0 + quad * 4) * S_DIM + key0 + n16;
        #pragma unroll
        for (int c = 0; c < 16; ++c) {
            #pragma unroll
            for (int r = 0; r < 4; ++r) arow[(size_t)r * S_DIM + c * 16] = sc[c][r];
        }
    }

    floatx4 o0 = {0,0,0,0}, o1 = {0,0,0,0}, o2 = {0,0,0,0}, o3 = {0,0,0,0};
    unsigned short* pw = pbuf + w * 576;
    #pragma unroll
    for (int s2 = 0; s2 < 8; ++s2) {
        #pragma unroll
        for (int h = 0; h < 2; ++h) {
            const int c = s2 * 2 + h;
            #pragma unroll
            for (int r = 0; r < 4; ++r)
                pw[(quad * 4 + r) * 36 + h * 16 + n16] = f2bf(sc[c][r]);
        }
        __syncthreads();
        short8 pa;
        {
            const uint32_t* pr = (const uint32_t*)((const char*)pbuf +
                                   (size_t)w * 1152 + n16 * 72 + quad * 16);
            union { uint32_t u[4]; short8 v; } P;
            P.u[0] = pr[0]; P.u[1] = pr[1]; P.u[2] = pr[2]; P.u[3] = pr[3];
            pa = P.v;
        }
        const size_t vrow0 = (size_t)(b * S_DIM + key0 + s2 * 32 + quad * 8) * D_DIM;
        #pragma unroll
        for (int nc = 0; nc < 4; ++nc) {
            const float* vp = v + vrow0 + nc * 16 + n16;
            union { __hip_bfloat162 h[4]; short8 v8; } BV;
            #pragma unroll
            for (int p = 0; p < 4; ++p) {
                float x0 = vp[(size_t)(2 * p) * D_DIM];
                float x1 = vp[(size_t)(2 * p + 1) * D_DIM];
                BV.h[p] = __float22bfloat162_rn(float2{x0, x1});
            }
            floatx4& oo = (nc == 0 ? o0 : nc == 1 ? o1 : nc == 2 ? o2 : o3);
            oo = __builtin_amdgcn_mfma_f32_16x16x32_bf16(pa, BV.v8, oo, 0, 0, 0);
        }
        __syncthreads();
    }

    #pragma unroll
    for (int nc = 0; nc < 4; ++nc) {
        floatx4 oo = (nc == 0 ? o0 : nc == 1 ? o1 : nc == 2 ? o2 : o3);
        #pragma unroll
        for (int i = 0; i < 4; ++i)
            obuf[(w * 16 + quad * 4 + i) * 68 + nc * 16 + n16] = oo[i];
    }
    __syncthreads();
    #pragma unroll
    for (int t2 = 0; t2 < 2; ++t2) {
        int idx = tid + t2 * 512;
        int m = idx >> 6, d = idx & 63;
        float a = 0.f;
        #pragma unroll
        for (int w2 = 0; w2 < 8; ++w2) a += obuf[(w2 * 16 + m) * 68 + d];
        out[(size_t)(b * S_DIM + q0 + m) * D_DIM + d] = a;
    }
}

extern "C" void kernel_launch(void* const* d_in, const int* in_sizes, int n_in,
                              void* d_out, int out_size, void* d_ws, size_t ws_size,
                              hipStream_t stream) {
    const float* q    = (const float*)d_in[0];
    const float* k    = (const float*)d_in[1];
    const float* v    = (const float*)d_in[2];
    const int*   mask = (const int*)d_in[3];

    float* out  = (float*)d_out;
    float* attn = out + (size_t)16 * S_DIM * D_DIM;   // 2,097,152 floats

    const size_t NE = (size_t)16 * S_DIM * D_DIM;     // 2,097,152 elements
    const size_t need = NE * 2 * 3 + NE * 4;          // khi2+klo2+vfrag (bf16) + bits (u32) = 20 MB
    if (d_ws != nullptr && ws_size >= need) {
        unsigned short* khi2  = (unsigned short*)d_ws;
        unsigned short* klo2  = khi2 + NE;
        unsigned short* vfrag = klo2 + NE;
        uint32_t*       bits  = (uint32_t*)(vfrag + NE);
        prep_all<<<dim3(10240), dim3(256), 0, stream>>>(mask, bits, k, khi2, klo2, v, vfrag);
        attn_fused_v4<<<dim3(2048), dim3(512), 0, stream>>>(q, khi2, klo2, vfrag, bits, out, attn);
    } else {
        attn_fused_v1<<<dim3(2048), dim3(512), 0, stream>>>(q, k, v, mask, out, attn);
    }
}